// Round 12
// baseline (189.701 us; speedup 1.0000x reference)
//
#include <hip/hip_runtime.h>

// Efficient (linear) attention, fused MFMA implementation for gfx950.  v8-r11
// B=4, NX=NY=16384, C=256, H=8, dk=dv=32.  M = B*N = 65536 rows.
// R6 change: fuse ctx into kv (kvctx_kernel). e/v never touch HBM: per block
// (64 rows = 2x32-row tiles) compute e,v tiles in LDS, accumulate per-head
// ctx partials E_h^T @ V_h via K=32 MFMAs + f32 denom via shuffle-reduce;
// write one 33KB partial per block; two-stage reduce -> ctxT. Deletes
// e_buf/v_buf (201 MB HBM traffic) and the ctx dispatch.

typedef float f32x4 __attribute__((ext_vector_type(4)));
typedef short s16x4 __attribute__((ext_vector_type(4)));
typedef short s16x8 __attribute__((ext_vector_type(8)));

#define MFMA16(A, B, C) __builtin_amdgcn_mfma_f32_16x16x32_bf16((A), (B), (C), 0, 0, 0)

__device__ __forceinline__ short f2bf(float f) {
    unsigned u = __builtin_bit_cast(unsigned, f);
    u = (u + 0x7FFFu + ((u >> 16) & 1u)) >> 16;   // RNE
    return (short)u;
}
__device__ __forceinline__ float bf2f(short b) {
    unsigned u = ((unsigned)(unsigned short)b) << 16;
    return __builtin_bit_cast(float, u);
}

// ---------------------------------------------------------------------------
// K0: convert 4 weight matrices to bf16 in MFMA-fragment-packed order.
// packed[m][tile][ks][lane][8] ; element = W[tile*16 + (lane&15)][ks*32 + (lane>>4)*8 + j]
// ---------------------------------------------------------------------------
__global__ __launch_bounds__(256) void wcvt_kernel(
    const float* __restrict__ wq, const float* __restrict__ wk,
    const float* __restrict__ wv, const float* __restrict__ wr,
    short* __restrict__ wbf)
{
    int id = blockIdx.x * 256 + threadIdx.x;     // grid 128 -> 32768 frag-slots
    int m = id >> 13;                            // matrix
    int slot = id & 8191;                        // tile(4b) ks(3b) lane(6b)
    int tile = slot >> 9;
    int ks   = (slot >> 6) & 7;
    int lane = slot & 63;
    int lrow = lane & 15, lgrp = lane >> 4;
    const float* src = (m == 0) ? wq : (m == 1) ? wk : (m == 2) ? wv : wr;
    const float* p = src + (size_t)(tile * 16 + lrow) * 256 + ks * 32 + lgrp * 8;
    f32x4 a = *(const f32x4*)p;
    f32x4 b = *(const f32x4*)(p + 4);
    s16x8 o;
    o[0]=f2bf(a[0]); o[1]=f2bf(a[1]); o[2]=f2bf(a[2]); o[3]=f2bf(a[3]);
    o[4]=f2bf(b[0]); o[5]=f2bf(b[1]); o[6]=f2bf(b[2]); o[7]=f2bf(b[3]);
    *(s16x8*)(wbf + (size_t)id * 8) = o;
}

// ---------------------------------------------------------------------------
// K1: fused kv+ctx.  256 thr (4 waves), 64 rows per block (2 tiles of 32),
// grid 1024, 32KB LDS.  Per tile: stage -> A-frags -> e/v GEMM -> C in LDS
// -> per-head ctx MFMA accumulate.  End: write partials[block][8448]
// ( [h][ck*32+cv] + [h][1024+ck]=denom ).
// ---------------------------------------------------------------------------
__global__ __launch_bounds__(256) void kvctx_kernel(
    const float* __restrict__ y, const float* __restrict__ ypos,
    const short* __restrict__ wkp, const short* __restrict__ wvp,
    const float* __restrict__ bk, const float* __restrict__ bv,
    float* __restrict__ partials)
{
    __shared__ short smem[32 * 512];             // 32KB: stage (ak|av) then C
    short* ak = smem;                            // [32][256] swizzled bf16(y+ypos)
    short* av = smem + 32 * 256;                 // [32][256] swizzled bf16(y)
    const int t = threadIdx.x;
    const int w = t >> 6, lane = t & 63;
    const int lrow = lane & 15, lgrp = lane >> 4;
    const bool is_k = (w < 2);                   // wave-uniform
    const int colbase = (w & 1) * 128;
    const int tile0 = colbase >> 4;
    const short* WP = is_k ? wkp : wvp;
    const float* bp = is_k ? bk : bv;
    const int row0 = blockIdx.x * 64;

    float bias[8];
    #pragma unroll
    for (int nf = 0; nf < 8; ++nf) bias[nf] = bp[colbase + nf * 16 + lrow];

    f32x4 cacc[2][2][2];                         // [hh][mfc][nfc]
    #pragma unroll
    for (int a = 0; a < 2; ++a)
      #pragma unroll
      for (int b = 0; b < 2; ++b)
        #pragma unroll
        for (int c = 0; c < 2; ++c) cacc[a][b][c] = (f32x4){0.f,0.f,0.f,0.f};
    float dacc[8];
    #pragma unroll
    for (int nf = 0; nf < 8; ++nf) dacc[nf] = 0.f;

    // prologue: issue tile-0 staging loads
    f32x4 ly[8], lp[8];
    #pragma unroll
    for (int it = 0; it < 8; ++it) {
        int r = it * 4 + w;
        ly[it] = *(const f32x4*)(y    + (size_t)(row0 + r) * 256 + lane * 4);
        lp[it] = *(const f32x4*)(ypos + (size_t)(row0 + r) * 256 + lane * 4);
    }

    for (int tt = 0; tt < 2; ++tt) {
        { // convert + LDS write (stage area)
            #pragma unroll
            for (int it = 0; it < 8; ++it) {
                int r = it * 4 + w;
                f32x4 a = ly[it];
                f32x4 k = a + lp[it];
                s16x4 ov, ok;
                ov[0]=f2bf(a[0]); ov[1]=f2bf(a[1]); ov[2]=f2bf(a[2]); ov[3]=f2bf(a[3]);
                ok[0]=f2bf(k[0]); ok[1]=f2bf(k[1]); ok[2]=f2bf(k[2]); ok[3]=f2bf(k[3]);
                int swz = ((lane >> 1) ^ (r & 7)) * 8 + (lane & 1) * 4;
                *(s16x4*)(av + r * 256 + swz) = ov;
                *(s16x4*)(ak + r * 256 + swz) = ok;
            }
        }
        __syncthreads();                          // B1: staging visible

        s16x8 af[2][8];
        {
            const short* A = is_k ? ak : av;
            #pragma unroll
            for (int mf = 0; mf < 2; ++mf) {
                int rr = mf * 16 + lrow;
                #pragma unroll
                for (int ks = 0; ks < 8; ++ks) {
                    int cs = ((ks * 4 + lgrp) ^ (rr & 7));
                    af[mf][ks] = *(const s16x8*)(A + rr * 256 + cs * 8);
                }
            }
        }
        if (tt == 0) {                            // issue tile-1 loads early
            #pragma unroll
            for (int it = 0; it < 8; ++it) {
                int r = it * 4 + w;
                ly[it] = *(const f32x4*)(y    + (size_t)(row0 + 32 + r) * 256 + lane * 4);
                lp[it] = *(const f32x4*)(ypos + (size_t)(row0 + 32 + r) * 256 + lane * 4);
            }
        }
        __syncthreads();                          // B2: A-reads done; smem -> C

        #pragma unroll
        for (int nf = 0; nf < 8; ++nf) {
            const int tile = tile0 + nf;
            const short* wt = WP + ((size_t)tile * 8) * 512 + lane * 8;
            f32x4 a0 = (f32x4){0.f, 0.f, 0.f, 0.f};
            f32x4 a1 = (f32x4){0.f, 0.f, 0.f, 0.f};
            #pragma unroll
            for (int kg = 0; kg < 2; ++kg) {
                s16x8 bf[4];
                #pragma unroll
                for (int kk = 0; kk < 4; ++kk)
                    bf[kk] = *(const s16x8*)(wt + (kg * 4 + kk) * 512);
                #pragma unroll
                for (int kk = 0; kk < 4; ++kk) {
                    a0 = MFMA16(af[0][kg * 4 + kk], bf[kk], a0);
                    a1 = MFMA16(af[1][kg * 4 + kk], bf[kk], a1);
                }
            }
            const int colp = (is_k ? 0 : 256) + colbase + nf * 16 + lrow;
            float ssum = 0.f;
            #pragma unroll
            for (int rr = 0; rr < 4; ++rr) {
                float v0 = a0[rr] + bias[nf];
                float v1 = a1[rr] + bias[nf];
                if (is_k) { v0 = __expf(v0); v1 = __expf(v1); ssum += v0 + v1; }
                int lr0 = lgrp * 4 + rr;
                int lr1 = lr0 + 16;
                smem[lr0 * 512 + (((colp >> 3) ^ (lr0 & 7)) * 8) + (colp & 7)] = f2bf(v0);
                smem[lr1 * 512 + (((colp >> 3) ^ (lr1 & 7)) * 8) + (colp & 7)] = f2bf(v1);
            }
            if (is_k) {                           // denom over this tile's 32 toks
                ssum += __shfl_xor(ssum, 16);
                ssum += __shfl_xor(ssum, 32);
                dacc[nf] += ssum;
            }
        }
        __syncthreads();                          // B3: C visible

        // ctx accumulate: wave w handles heads 2w, 2w+1
        #pragma unroll
        for (int hh = 0; hh < 2; ++hh) {
            const int h = w * 2 + hh;
            s16x8 ea[2], vb[2];
            #pragma unroll
            for (int mfc = 0; mfc < 2; ++mfc) {
                int colp = h * 32 + mfc * 16 + lrow;          // e col
                #pragma unroll
                for (int j = 0; j < 8; ++j) {
                    int tok = lgrp * 8 + j;
                    ea[mfc][j] = smem[tok * 512 + (((colp >> 3) ^ (tok & 7)) * 8) + (colp & 7)];
                }
            }
            #pragma unroll
            for (int nfc = 0; nfc < 2; ++nfc) {
                int colp = 256 + h * 32 + nfc * 16 + lrow;    // v col
                #pragma unroll
                for (int j = 0; j < 8; ++j) {
                    int tok = lgrp * 8 + j;
                    vb[nfc][j] = smem[tok * 512 + (((colp >> 3) ^ (tok & 7)) * 8) + (colp & 7)];
                }
            }
            #pragma unroll
            for (int mfc = 0; mfc < 2; ++mfc)
                #pragma unroll
                for (int nfc = 0; nfc < 2; ++nfc)
                    cacc[hh][mfc][nfc] = MFMA16(ea[mfc], vb[nfc], cacc[hh][mfc][nfc]);
        }
        __syncthreads();                          // B4: ctx reads done; smem free
    }

    // write partials: [h][ck*32+cv] and [h][1024+ck]
    float* P = partials + (size_t)blockIdx.x * 8448;
    #pragma unroll
    for (int hh = 0; hh < 2; ++hh) {
        const int h = w * 2 + hh;
        #pragma unroll
        for (int mfc = 0; mfc < 2; ++mfc)
            #pragma unroll
            for (int nfc = 0; nfc < 2; ++nfc)
                #pragma unroll
                for (int rr = 0; rr < 4; ++rr) {
                    int ck = mfc * 16 + lgrp * 4 + rr;
                    int cv = nfc * 16 + lrow;
                    P[h * 1056 + ck * 32 + cv] = cacc[hh][mfc][nfc][rr];
                }
    }
    if (is_k && lgrp == 0) {
        #pragma unroll
        for (int nf = 0; nf < 8; ++nf) {
            int col = colbase + nf * 16 + lrow;
            P[(col >> 5) * 1056 + 1024 + (col & 31)] = dacc[nf];
        }
    }
}

// ---------------------------------------------------------------------------
// K2a: reduce stage 1: grid (8 slabs, 32 bh).  Sum 32 block-partials.
// ---------------------------------------------------------------------------
__global__ __launch_bounds__(256) void ctxred1_kernel(
    const float* __restrict__ partials, float* __restrict__ inter)
{
    const int slab = blockIdx.x, bh = blockIdx.y;
    const int b = bh >> 3, h = bh & 7;
    const int t = threadIdx.x;
    const float* base = partials + ((size_t)(b * 256 + slab * 32)) * 8448 + h * 1056;
    float* obase = inter + (size_t)(bh * 8 + slab) * 1056;
    for (int e = t; e < 1056; e += 256) {
        float a = 0.f;
        #pragma unroll 4
        for (int i = 0; i < 32; ++i) a += base[(size_t)i * 8448 + e];
        obase[e] = a;
    }
}

// K2b: reduce stage 2 + normalize; write ctx^T bf16 [bh][cv][ck]
__global__ __launch_bounds__(256) void ctxred2_kernel(
    const float* __restrict__ inter, short* __restrict__ ctxT)
{
    __shared__ float s[1056];
    const int bh = blockIdx.x, t = threadIdx.x;
    for (int e = t; e < 1056; e += 256) {
        float a = 0.f;
        #pragma unroll
        for (int i = 0; i < 8; ++i) a += inter[(size_t)(bh * 8 + i) * 1056 + e];
        s[e] = a;
    }
    __syncthreads();
    for (int e = t; e < 1024; e += 256) {
        int ck = e >> 5, cv = e & 31;
        float val = s[e] / s[1024 + ck];
        ctxT[(size_t)bh * 1024 + cv * 32 + ck] = f2bf(val);
    }
}

// ---------------------------------------------------------------------------
// K3: fused q pass.  256 thr, 32 rows, grid 2048.  (unchanged from v7)
// ---------------------------------------------------------------------------
__global__ __launch_bounds__(256) void qout_kernel(
    const float* __restrict__ x, const float* __restrict__ xpos,
    const short* __restrict__ wqp, const float* __restrict__ bq,
    const short* __restrict__ ctxT,
    const short* __restrict__ wrp, const float* __restrict__ br,
    float* __restrict__ out)
{
    __shared__ short alds[32 * 256];
    __shared__ short qlds[4][32 * 64];
    const int row0 = blockIdx.x * 32;
    const int b = row0 >> 14;
    const int t = threadIdx.x;
    const int w = t >> 6, lane = t & 63;

    {
        f32x4 lx[8], lp[8];
        #pragma unroll
        for (int it = 0; it < 8; ++it) {
            int r = it * 4 + w;
            lx[it] = *(const f32x4*)(x    + (size_t)(row0 + r) * 256 + lane * 4);
            lp[it] = *(const f32x4*)(xpos + (size_t)(row0 + r) * 256 + lane * 4);
        }
        #pragma unroll
        for (int it = 0; it < 8; ++it) {
            int r = it * 4 + w;
            f32x4 a = lx[it] + lp[it];
            s16x4 o;
            o[0]=f2bf(a[0]); o[1]=f2bf(a[1]); o[2]=f2bf(a[2]); o[3]=f2bf(a[3]);
            int swz = ((lane >> 1) ^ (r & 7)) * 8 + (lane & 1) * 4;
            *(s16x4*)(alds + r * 256 + swz) = o;
        }
    }
    __syncthreads();

    const int lrow = lane & 15, lgrp = lane >> 4;
    const int wc = w * 64;
    const int tile0 = wc >> 4;

    float biasq[4];
    #pragma unroll
    for (int nf = 0; nf < 4; ++nf) biasq[nf] = bq[wc + nf * 16 + lrow];

    f32x4 acc[2][4];
    #pragma unroll
    for (int mf = 0; mf < 2; ++mf)
        #pragma unroll
        for (int nf = 0; nf < 4; ++nf) acc[mf][nf] = (f32x4){0.f, 0.f, 0.f, 0.f};

    {
        const short* wq8 = wqp + lane * 8;
        s16x8 bfq[2][4];
        #pragma unroll
        for (int nf = 0; nf < 4; ++nf)
            bfq[0][nf] = *(const s16x8*)(wq8 + ((size_t)(tile0 + nf) * 8 + 0) * 512);
        #pragma unroll
        for (int ks = 0; ks < 8; ++ks) {
            const int cur = ks & 1, nxt = cur ^ 1;
            if (ks < 7) {
                #pragma unroll
                for (int nf = 0; nf < 4; ++nf)
                    bfq[nxt][nf] = *(const s16x8*)(wq8 + ((size_t)(tile0 + nf) * 8 + ks + 1) * 512);
            }
            s16x8 af[2];
            #pragma unroll
            for (int mf = 0; mf < 2; ++mf) {
                int rr = mf * 16 + lrow;
                int cs = (ks * 4 + lgrp) ^ (rr & 7);
                af[mf] = *(const s16x8*)(alds + rr * 256 + cs * 8);
            }
            #pragma unroll
            for (int nf = 0; nf < 4; ++nf) {
                acc[0][nf] = MFMA16(af[0], bfq[cur][nf], acc[0][nf]);
                acc[1][nf] = MFMA16(af[1], bfq[cur][nf], acc[1][nf]);
            }
        }
    }

    short* ql = (short*)qlds[w];
    #pragma unroll
    for (int mf = 0; mf < 2; ++mf) {
        f32x4 e[4];
        #pragma unroll
        for (int nf = 0; nf < 4; ++nf)
            #pragma unroll
            for (int rr = 0; rr < 4; ++rr)
                e[nf][rr] = __expf(acc[mf][nf][rr] + biasq[nf]);
        #pragma unroll
        for (int hl = 0; hl < 2; ++hl) {
            #pragma unroll
            for (int rr = 0; rr < 4; ++rr) {
                float s = e[hl * 2][rr] + e[hl * 2 + 1][rr];
                s += __shfl_xor(s, 1);
                s += __shfl_xor(s, 2);
                s += __shfl_xor(s, 4);
                s += __shfl_xor(s, 8);
                float rinv = 1.0f / s;
                int row = mf * 16 + lgrp * 4 + rr;
                #pragma unroll
                for (int n2 = 0; n2 < 2; ++n2) {
                    int colc = hl * 32 + n2 * 16 + lrow;
                    int cs = (colc >> 3) ^ (row & 7);
                    ql[row * 64 + cs * 8 + (colc & 7)] = f2bf(e[hl * 2 + n2][rr] * rinv);
                }
            }
        }
    }
    __syncthreads();

    f32x4 att[2][2][2];
    #pragma unroll
    for (int hl = 0; hl < 2; ++hl)
        #pragma unroll
        for (int mf = 0; mf < 2; ++mf)
            #pragma unroll
            for (int n2 = 0; n2 < 2; ++n2) att[hl][mf][n2] = (f32x4){0.f,0.f,0.f,0.f};

    #pragma unroll
    for (int hl = 0; hl < 2; ++hl) {
        const short* cbase = ctxT + (size_t)(b * 8 + w * 2 + hl) * 1024;
        s16x8 bctx[2];
        #pragma unroll
        for (int n2 = 0; n2 < 2; ++n2)
            bctx[n2] = *(const s16x8*)(cbase + (n2 * 16 + lrow) * 32 + lgrp * 8);
        #pragma unroll
        for (int mf = 0; mf < 2; ++mf) {
            int row = mf * 16 + lrow;
            int cs = (hl * 4 + lgrp) ^ (row & 7);
            s16x8 aq = *(const s16x8*)(ql + row * 64 + cs * 8);
            #pragma unroll
            for (int n2 = 0; n2 < 2; ++n2)
                att[hl][mf][n2] = MFMA16(aq, bctx[n2], att[hl][mf][n2]);
        }
    }

    #pragma unroll
    for (int hl = 0; hl < 2; ++hl)
      #pragma unroll
      for (int mf = 0; mf < 2; ++mf)
        #pragma unroll
        for (int n2 = 0; n2 < 2; ++n2)
          #pragma unroll
          for (int rr = 0; rr < 4; ++rr) {
              int row = mf * 16 + lgrp * 4 + rr;
              int col = wc + hl * 32 + n2 * 16 + lrow;
              int cs = (col >> 3) ^ (row & 7);
              alds[row * 256 + cs * 8 + (col & 7)] = f2bf(att[hl][mf][n2][rr]);
          }
    __syncthreads();

    float biasr[4];
    #pragma unroll
    for (int nf = 0; nf < 4; ++nf) biasr[nf] = br[wc + nf * 16 + lrow];

    f32x4 acc2[2][4];
    #pragma unroll
    for (int mf = 0; mf < 2; ++mf)
        #pragma unroll
        for (int nf = 0; nf < 4; ++nf) acc2[mf][nf] = (f32x4){0.f, 0.f, 0.f, 0.f};

    {
        const short* wr8 = wrp + lane * 8;
        s16x8 bfr[2][4];
        #pragma unroll
        for (int nf = 0; nf < 4; ++nf)
            bfr[0][nf] = *(const s16x8*)(wr8 + ((size_t)(tile0 + nf) * 8 + 0) * 512);
        #pragma unroll
        for (int ks = 0; ks < 8; ++ks) {
            const int cur = ks & 1, nxt = cur ^ 1;
            if (ks < 7) {
                #pragma unroll
                for (int nf = 0; nf < 4; ++nf)
                    bfr[nxt][nf] = *(const s16x8*)(wr8 + ((size_t)(tile0 + nf) * 8 + ks + 1) * 512);
            }
            s16x8 af[2];
            #pragma unroll
            for (int mf = 0; mf < 2; ++mf) {
                int rr = mf * 16 + lrow;
                int cs = (ks * 4 + lgrp) ^ (rr & 7);
                af[mf] = *(const s16x8*)(alds + rr * 256 + cs * 8);
            }
            #pragma unroll
            for (int nf = 0; nf < 4; ++nf) {
                acc2[0][nf] = MFMA16(af[0], bfr[cur][nf], acc2[0][nf]);
                acc2[1][nf] = MFMA16(af[1], bfr[cur][nf], acc2[1][nf]);
            }
        }
    }

    #pragma unroll
    for (int mf = 0; mf < 2; ++mf)
      #pragma unroll
      for (int nf = 0; nf < 4; ++nf)
        #pragma unroll
        for (int rr = 0; rr < 4; ++rr) {
            int grow = row0 + mf * 16 + lgrp * 4 + rr;
            out[(size_t)grow * 256 + wc + nf * 16 + lrow] = acc2[mf][nf][rr] + biasr[nf];
        }
}

// ---------------------------------------------------------------------------
extern "C" void kernel_launch(void* const* d_in, const int* in_sizes, int n_in,
                              void* d_out, int out_size, void* d_ws, size_t ws_size,
                              hipStream_t stream)
{
    const float* x    = (const float*)d_in[0];
    const float* y    = (const float*)d_in[1];
    const float* xpos = (const float*)d_in[2];
    const float* ypos = (const float*)d_in[3];
    const float* Wq   = (const float*)d_in[4];
    const float* bq   = (const float*)d_in[5];
    const float* Wk   = (const float*)d_in[6];
    const float* bk   = (const float*)d_in[7];
    const float* Wv   = (const float*)d_in[8];
    const float* bv   = (const float*)d_in[9];
    const float* Wr   = (const float*)d_in[10];
    const float* br   = (const float*)d_in[11];

    char*  ws    = (char*)d_ws;
    short* wbf   = (short*)(ws);                     // 512 KB packed weights
    short* ctxT  = (short*)(ws + 524288);            // 64 KB
    float* inter = (float*)(ws + (2u << 20));        // 32*8*1056 f32 ~1.1 MB
    float* parts = (float*)(ws + ((size_t)4 << 20)); // 1024*8448 f32 ~34.6 MB
    float* outp  = (float*)d_out;

    hipLaunchKernelGGL(wcvt_kernel, dim3(128), dim3(256), 0, stream,
                       Wq, Wk, Wv, Wr, wbf);
    hipLaunchKernelGGL(kvctx_kernel, dim3(1024), dim3(256), 0, stream,
                       y, ypos, wbf + 65536, wbf + 131072, bk, bv, parts);
    hipLaunchKernelGGL(ctxred1_kernel, dim3(8, 32), dim3(256), 0, stream,
                       parts, inter);
    hipLaunchKernelGGL(ctxred2_kernel, dim3(32), dim3(256), 0, stream,
                       inter, ctxT);
    hipLaunchKernelGGL(qout_kernel, dim3(2048), dim3(256), 0, stream,
                       x, xpos, wbf, bq, ctxT, wbf + 196608, br, outp);
}